// Round 8
// baseline (71.865 us; speedup 1.0000x reference)
//
#include <hip/hip_runtime.h>
#include <math.h>

#define CHUNK 1024     // simplices per ect block
#define RSL 4          // reduction slices
#define FPS 32768.0f   // fixed-point scale 2^15 for transition sums

// K1: nh[n][t] = x[n].v[:,t]. One thread per node, 32 outputs via float4.
// Block 0 thread 0 also resets the redfin ticket counter (deterministic
// per-launch init without an extra memset dispatch).
__global__ __launch_bounds__(256) void nh_kernel(const float* __restrict__ x,
    const float* __restrict__ v, float* __restrict__ nh, int* __restrict__ done,
    int N) {
  __shared__ float vs[96];
  int tid = threadIdx.x;
  if (tid < 96) vs[tid] = v[tid];
  if (blockIdx.x == 0 && tid == 0)
    __hip_atomic_store(done, 0, __ATOMIC_RELAXED, __HIP_MEMORY_SCOPE_AGENT);
  __syncthreads();
  int n = blockIdx.x * 256 + tid;
  if (n >= N) return;
  float x0 = x[3 * n], x1 = x[3 * n + 1], x2 = x[3 * n + 2];
  float4* row = (float4*)(nh + (size_t)n * 32);
#pragma unroll
  for (int i = 0; i < 8; ++i) {
    float4 r;
    r.x = fmaf(x0, vs[4 * i + 0], fmaf(x1, vs[32 + 4 * i + 0], x2 * vs[64 + 4 * i + 0]));
    r.y = fmaf(x0, vs[4 * i + 1], fmaf(x1, vs[32 + 4 * i + 1], x2 * vs[64 + 4 * i + 1]));
    r.z = fmaf(x0, vs[4 * i + 2], fmaf(x1, vs[32 + 4 * i + 2], x2 * vs[64 + 4 * i + 2]));
    r.w = fmaf(x0, vs[4 * i + 3], fmaf(x1, vs[32 + 4 * i + 3], x2 * vs[64 + 4 * i + 3]));
    row[i] = r;
  }
}

// K2: raw-order saturation-split ECT. Block = (chunk of 1024 simplices,
// theta-half hf). LDS hist [arr][g][bin][t16] = 32 KB, int atomics only.
// Simplices are ordered [nodes | edges | faces] -> three branch-free loops
// so the compiler can pipeline the idx->nh gather chains.
// Flush = plain coalesced int4 stores. No global atomics.
__global__ __launch_bounds__(512) void ect_kernel(const float* __restrict__ nh,
    const int* __restrict__ ei, const int* __restrict__ face,
    const int* __restrict__ batch, const float* __restrict__ lin,
    const int* __restrict__ scale_p, int* __restrict__ partial,
    int N, int E, int F, int M) {
  __shared__ alignas(16) int hist[8192];  // arr*4096 + g*512 + bin*16 + t16
  int tid = threadIdx.x, bid = blockIdx.x;
  int c = bid >> 1, hf = bid & 1;
#pragma unroll
  for (int i = 0; i < 4; ++i)
    ((int4*)hist)[tid + 512 * i] = int4{0, 0, 0, 0};
  __syncthreads();

  int t16 = tid & 15, srow = tid >> 4;    // srow 0..31
  int tt = (hf << 4) + t16;               // global theta
  int start = c * CHUNK;
  int end = min(start + CHUNK, M);

  float scale = (float)scale_p[0];
  float lin0 = lin[0];
  float step = (lin[31] - lin0) * (1.f / 31.f);
  float istep = 1.f / step;
  float Cl = scale * step * 1.44269504088896f;  // log2-slope per bin
  float w = 13.f / (scale * step);              // transition half-width (bins)

  auto deposit = [&](float h, int g, int isn) {
    float kf = (h - lin0) * istep;
    int b0 = (int)ceilf(kf - w);
    int b1 = (int)floorf(kf + w);
    int fs = max(b1 + 1, 0);
    int gb = g << 9;
    if (fs <= 31) atomicAdd(&hist[gb + (fs << 4) + t16], isn);
    float q = Cl * kf;
    float fsn = (float)isn;
    int blo = max(b0, 0), bhi = min(b1, 31);
    for (int b = blo; b <= bhi; ++b) {
      float e2 = __builtin_amdgcn_exp2f(fmaf(-Cl, (float)b, q));
      float val = fsn * __builtin_amdgcn_rcpf(1.f + e2);
      atomicAdd(&hist[4096 + gb + (b << 4) + t16], (int)rintf(val * FPS));
    }
  };

  // nodes
  int e0 = min(end, N);
  for (int m = start + srow; m < e0; m += 32)
    deposit(nh[(size_t)m * 32 + tt], batch[m], 1);
  // edges
  int s1 = max(start, N), e1 = min(end, N + E);
  for (int m = s1 + srow; m < e1; m += 32) {
    int e = m - N;
    int n0 = ei[e], n1 = ei[E + e];
    float h = fmaxf(nh[(size_t)n0 * 32 + tt], nh[(size_t)n1 * 32 + tt]);
    deposit(h, batch[n0], -1);
  }
  // faces
  int s2 = max(start, N + E);
  for (int m = s2 + srow; m < end; m += 32) {
    int f = m - N - E;
    int n0 = face[f], n1 = face[F + f], n2 = face[2 * F + f];
    float h = fmaxf(fmaxf(nh[(size_t)n0 * 32 + tt], nh[(size_t)n1 * 32 + tt]),
                    nh[(size_t)n2 * 32 + tt]);
    deposit(h, batch[n0], 1);
  }
  __syncthreads();
  int4* dst = (int4*)(partial + (size_t)bid * 8192);
  const int4* src = (const int4*)hist;
#pragma unroll
  for (int i = 0; i < 4; ++i)
    dst[tid + 512 * i] = src[tid + 512 * i];
}

// K3: tree reduce over chunks + fused last-block finisher.
// 256 blocks: s = bid>>6 (0..3), cg = bid&63; cell cid = cg*256+tid.
// cid = hf*8192 + (arr*4096 + g*512 + bin*16 + t16).
// Last block: per (g,theta) column prefix of markers over bins, add
// fractional transitions, per-graph max (half-wave shuffle), normalize.
__global__ __launch_bounds__(256) void redfin_kernel(const int* __restrict__ partial,
    int* __restrict__ part2, int* __restrict__ done, float* __restrict__ out,
    int nchunk) {
  int tid = threadIdx.x, bid = blockIdx.x;
  int s = bid >> 6, cg = bid & 63;
  int cid = cg * 256 + tid;
  int hf = cid >> 13, j = cid & 8191;
  int sum = 0;
  for (int cc = s; cc < nchunk; cc += RSL)
    sum += partial[(size_t)(cc * 2 + hf) * 8192 + j];
  part2[s * 16384 + cid] = sum;

  __threadfence();
  __shared__ int amLast;
  if (tid == 0) amLast = (atomicAdd(done, 1) == 255);
  __syncthreads();
  if (!amLast) return;

  int g = tid >> 5, t = tid & 31;
  int hf2 = t >> 4, t16 = t & 15;
  int base_c = (hf2 << 13) + (g << 9) + t16;  // + (k<<4); transitions +4096
  float r[32];
  int runc = 0;
  float mx = -1e30f;
#pragma unroll
  for (int k = 0; k < 32; ++k) {
    int sc = 0, sa = 0;
#pragma unroll
    for (int s2 = 0; s2 < RSL; ++s2) {
      sc += __hip_atomic_load(&part2[s2 * 16384 + base_c + (k << 4)],
                              __ATOMIC_RELAXED, __HIP_MEMORY_SCOPE_AGENT);
      sa += __hip_atomic_load(&part2[s2 * 16384 + base_c + 4096 + (k << 4)],
                              __ATOMIC_RELAXED, __HIP_MEMORY_SCOPE_AGENT);
    }
    runc += sc;
    r[k] = (float)runc + (float)sa * (1.f / FPS);
    mx = fmaxf(mx, r[k]);
  }
#pragma unroll
  for (int off = 1; off < 32; off <<= 1) mx = fmaxf(mx, __shfl_xor(mx, off));
  float imx = 1.f / mx;
#pragma unroll
  for (int k = 0; k < 32; ++k)
    out[(g << 10) + (k << 5) + t] = r[k] * imx;
}

extern "C" void kernel_launch(void* const* d_in, const int* in_sizes, int n_in,
                              void* d_out, int out_size, void* d_ws, size_t ws_size,
                              hipStream_t stream) {
  const float* x     = (const float*)d_in[0];
  const float* v     = (const float*)d_in[1];
  const float* lin   = (const float*)d_in[2];
  const int*   ei    = (const int*)d_in[3];
  const int*   face  = (const int*)d_in[4];
  const int*   batch = (const int*)d_in[5];
  const int*   scale = (const int*)d_in[6];
  const int N = in_sizes[5];
  const int E = in_sizes[3] / 2;
  const int F = in_sizes[4] / 3;
  const int M = N + E + F;
  const int nchunk = (M + CHUNK - 1) / CHUNK;

  float* nh      = (float*)d_ws;                        // N*32 f32
  int*   partial = (int*)(nh + (size_t)N * 32);         // 2*nchunk*8192 ints
  int*   part2   = partial + (size_t)2 * nchunk * 8192; // RSL*16384 ints
  int*   done    = part2 + RSL * 16384;                 // 1 int

  nh_kernel<<<(N + 255) / 256, 256, 0, stream>>>(x, v, nh, done, N);
  ect_kernel<<<2 * nchunk, 512, 0, stream>>>(nh, ei, face, batch, lin, scale,
                                             partial, N, E, F, M);
  redfin_kernel<<<64 * RSL, 256, 0, stream>>>(partial, part2, done,
                                              (float*)d_out, nchunk);
}